// Round 6
// baseline (187.447 us; speedup 1.0000x reference)
//
#include <hip/hip_runtime.h>

#define NH  32
#define SEQ 2048
#define DIM 128
#define FD  32

typedef short          short8 __attribute__((ext_vector_type(8)));
typedef float          f32x4  __attribute__((ext_vector_type(4)));
typedef unsigned short u16x8  __attribute__((ext_vector_type(8)));

static __device__ __forceinline__ unsigned short f2bf(float f) {
    unsigned int u = __builtin_bit_cast(unsigned int, f);
    u += 0x7fffu + ((u >> 16) & 1u);            // round-to-nearest-even
    return (unsigned short)(u >> 16);
}
static __device__ __forceinline__ float fexp(float x) {          // e^x
    return __builtin_amdgcn_exp2f(x * 1.44269504088896f);
}
static __device__ __forceinline__ float sigm(float x) {
    return __builtin_amdgcn_rcpf(1.0f + fexp(-x));
}
static __device__ __forceinline__ float silu_f(float x) { return x * sigm(x); }
static __device__ __forceinline__ float tanh_f(float x) {
    return 1.0f - 2.0f * __builtin_amdgcn_rcpf(fexp(2.0f * x) + 1.0f);
}

// ---------------------------------------------------------------------------
// Weight image in d_ws (ushort units), per src (0=K,1=Q), per head:
//   [W1: 128x128][W2: 128x128][W3: 32x128] bf16, rows XOR-swizzled:
//   element (r,c) stored at r*128 + (c ^ ((r&7)<<3))  (8-ushort block XOR).
#define WPH 36864
#define WPS (32 * WPH)

__global__ __launch_bounds__(256) void prep_weights(
    const float* __restrict__ Wk1, const float* __restrict__ Wk2,
    const float* __restrict__ Wk3, const float* __restrict__ Wq1,
    const float* __restrict__ Wq2, const float* __restrict__ Wq3,
    unsigned short* __restrict__ wimg) {
    int c = blockIdx.x * 256 + threadIdx.x;    // 294912 chunks of 8 elems
    int s = (c >= 147456) ? 1 : 0;
    c -= s * 147456;
    const float* src;
    int dst;
    int sB = s * WPS;
    if (c < 65536) {                            // W1
        int h = c >> 11, idx = c & 2047;
        int r = idx >> 4, jb = (idx & 15) * 8;
        src = (s ? Wq1 : Wk1) + h * 16384 + r * 128 + jb;
        dst = sB + h * WPH + r * 128 + (jb ^ ((r & 7) << 3));
    } else if (c < 131072) {                    // W2
        int cc = c - 65536;
        int h = cc >> 11, idx = cc & 2047;
        int r = idx >> 4, jb = (idx & 15) * 8;
        src = (s ? Wq2 : Wk2) + h * 16384 + r * 128 + jb;
        dst = sB + h * WPH + 16384 + r * 128 + (jb ^ ((r & 7) << 3));
    } else {                                    // W3
        int cc = c - 131072;
        int h = cc >> 9, idx = cc & 511;
        int r = idx >> 4, jb = (idx & 15) * 8;
        src = (s ? Wq3 : Wk3) + h * 4096 + r * 128 + jb;
        dst = sB + h * WPH + 32768 + r * 128 + (jb ^ ((r & 7) << 3));
    }
    f32x4 u0 = *(const f32x4*)src;
    f32x4 u1 = *(const f32x4*)(src + 4);
    u16x8 p;
    p[0] = f2bf(u0[0]); p[1] = f2bf(u0[1]); p[2] = f2bf(u0[2]); p[3] = f2bf(u0[3]);
    p[4] = f2bf(u1[0]); p[5] = f2bf(u1[1]); p[6] = f2bf(u1[2]); p[7] = f2bf(u1[3]);
    *(u16x8*)(&wimg[dst]) = p;
}

// ---------------------------------------------------------------------------
// MLP (byte-identical to rounds 4/5)
template <int OT, int ACT, bool LIN>
static __device__ __forceinline__ void compute_layer(
    const short8 a[4], const unsigned short* W,
    const float* __restrict__ bias, unsigned short* dst, int lane, int wid) {
    int r0 = lane & 15, q = lane >> 4, kb = q * 8;
#pragma unroll
    for (int ot = 0; ot < OT; ++ot) {
        int wrow = ot * 16 + r0;
        int sw   = (wrow & 7) << 3;
        short8 b[4];
#pragma unroll
        for (int ks = 0; ks < 4; ++ks)
            b[ks] = *(const short8*)(&W[wrow * 128 + ((ks * 32 + kb) ^ sw)]);
        f32x4 acc = {0.f, 0.f, 0.f, 0.f};
#pragma unroll
        for (int ks = 0; ks < 4; ++ks)
            acc = __builtin_amdgcn_mfma_f32_16x16x32_bf16(a[ks], b[ks], acc, 0, 0, 0);
        float bv = bias[wrow];
#pragma unroll
        for (int r = 0; r < 4; ++r) {
            float y = acc[r] + bv;
            float v = (ACT == 0) ? silu_f(y) : tanh_f(y);
            int orow = wid * 16 + q * 4 + r;
            int ocol = ot * 16 + r0;
            if (LIN)
                dst[orow * FD + ocol] = f2bf(v);
            else
                dst[orow * 128 + (ocol ^ ((orow & 7) << 3))] = f2bf(v);
        }
    }
}

__global__ __launch_bounds__(256) void mlp_kernel(
    const float* __restrict__ K,  const float* __restrict__ Q,
    const float* __restrict__ bk1, const float* __restrict__ bk2,
    const float* __restrict__ bk3, const float* __restrict__ bq1,
    const float* __restrict__ bq2, const float* __restrict__ bq3,
    const unsigned short* __restrict__ wimg,
    unsigned short* __restrict__ Kl, unsigned short* __restrict__ Ql) {
    __shared__ unsigned short wb[128 * 128];   // 32 KB  W1 then W2
    __shared__ unsigned short w3[32 * 128];    // 8 KB
    __shared__ unsigned short act[64 * 128];   // 16 KB
    __shared__ unsigned short outb[64 * FD];   // 4 KB   -> 60 KB total
    int raw = blockIdx.x;
    int bid = (raw & 7) * 256 + (raw >> 3);    // XCD swizzle (2048 % 8 == 0)
    int tb  = bid & 31;
    int h   = (bid >> 5) & 31;
    int s   = bid >> 10;

    const float* X  = s ? Q : K;
    const unsigned short* Wb = wimg + s * WPS + h * WPH;
    const float* B1 = (s ? bq1 : bk1) + h * 128;
    const float* B2 = (s ? bq2 : bk2) + h * 128;
    const float* B3 = (s ? bq3 : bk3) + h * FD;
    unsigned short* gout = (s ? Ql : Kl) + ((size_t)h * SEQ + (size_t)tb * 64) * FD;

    int tid = threadIdx.x, lane = tid & 63, wid = tid >> 6;
    int r0 = lane & 15, kb = (lane >> 4) * 8;

    const u16x8* wsrc = (const u16x8*)Wb;
#pragma unroll
    for (int i = 0; i < 8; ++i)
        *(u16x8*)(&wb[(i * 256 + tid) * 8]) = wsrc[i * 256 + tid];
    const u16x8* w3src = (const u16x8*)(Wb + 32768);
#pragma unroll
    for (int i = 0; i < 2; ++i)
        *(u16x8*)(&w3[(i * 256 + tid) * 8]) = w3src[i * 256 + tid];

    short8 a[4];
    const float* xs = X + ((size_t)h * SEQ + (size_t)tb * 64) * DIM;
    int row = wid * 16 + r0;
#pragma unroll
    for (int ks = 0; ks < 4; ++ks) {
        const float* p = xs + row * 128 + ks * 32 + kb;
        f32x4 u0 = *(const f32x4*)p;
        f32x4 u1 = *(const f32x4*)(p + 4);
        short8 t;
        t[0] = f2bf(u0[0]); t[1] = f2bf(u0[1]); t[2] = f2bf(u0[2]); t[3] = f2bf(u0[3]);
        t[4] = f2bf(u1[0]); t[5] = f2bf(u1[1]); t[6] = f2bf(u1[2]); t[7] = f2bf(u1[3]);
        a[ks] = t;
    }
    __syncthreads();
    compute_layer<8, 0, false>(a, wb, B1, act, lane, wid);   // h1 -> act
    __syncthreads();
#pragma unroll
    for (int i = 0; i < 8; ++i)
        *(u16x8*)(&wb[(i * 256 + tid) * 8]) = wsrc[2048 + i * 256 + tid];
    __syncthreads();
    {
        int sw = (row & 7) << 3;
#pragma unroll
        for (int ks = 0; ks < 4; ++ks)
            a[ks] = *(const short8*)(&act[row * 128 + ((ks * 32 + kb) ^ sw)]);
    }
    compute_layer<8, 0, false>(a, wb, B2, act, lane, wid);   // h2 -> act
    {
        int sw = (row & 7) << 3;
#pragma unroll
        for (int ks = 0; ks < 4; ++ks)
            a[ks] = *(const short8*)(&act[row * 128 + ((ks * 32 + kb) ^ sw)]);
    }
    compute_layer<2, 1, true>(a, w3, B3, outb, lane, wid);   // out -> outb
    __syncthreads();
    *(u16x8*)(gout + tid * 8) = *(const u16x8*)(&outb[tid * 8]);
}

// ---------------------------------------------------------------------------
// score (byte-identical to round 5)
__global__ __launch_bounds__(256) void score_kernel(
    const unsigned short* __restrict__ Ql, const unsigned short* __restrict__ Kl,
    float* __restrict__ out) {
    int bid = blockIdx.x;
    int h   = bid >> 8;
    int tr  = (bid >> 4) & 15;
    int tc  = bid & 15;
    int tq0 = tr * 128, tk0 = tc * 128;
    int tid = threadIdx.x;
    float* ob = out + (size_t)h * SEQ * SEQ;

    if (tc > tr) {                              // fully masked: sigmoid(-inf) = 0
        f32x4 z = {0.f, 0.f, 0.f, 0.f};
        for (int it = 0; it < 16; ++it) {
            int row = tq0 + it * 8 + (tid >> 5);
            int c0  = tk0 + (tid & 31) * 4;
            *(f32x4*)(ob + (size_t)row * SEQ + c0) = z;
        }
        return;
    }
    bool diag = (tc == tr);
    __shared__ float sb[4][16 * 68];            // 17 KB, per-wave private
    int lane = tid & 63;
    int wid  = tid >> 6;
    int tqw  = tq0 + (wid >> 1) * 64;
    int tkw  = tk0 + (wid & 1) * 64;
    int kb   = (lane >> 4) * 8;

    short8 aq[4], bk[4];
#pragma unroll
    for (int i = 0; i < 4; ++i) {
        aq[i] = *(const short8*)(Ql + ((size_t)h * SEQ + tqw + i * 16 + (lane & 15)) * FD + kb);
        bk[i] = *(const short8*)(Kl + ((size_t)h * SEQ + tkw + i * 16 + (lane & 15)) * FD + kb);
    }
    float* my = sb[wid];
#pragma unroll
    for (int qr = 0; qr < 4; ++qr) {            // 16-row strip
#pragma unroll
        for (int ct = 0; ct < 4; ++ct) {
            f32x4 acc = {0.f, 0.f, 0.f, 0.f};
            acc = __builtin_amdgcn_mfma_f32_16x16x32_bf16(aq[qr], bk[ct], acc, 0, 0, 0);
#pragma unroll
            for (int r = 0; r < 4; ++r) {
                int lr  = (lane >> 4) * 4 + r;            // 0..15
                int col = ct * 16 + (lane & 15);
                float o = sigm(acc[r] - 0.5f);
                if (diag && (tkw + col) > (tqw + qr * 16 + lr)) o = 0.0f;
                my[lr * 68 + col] = o;
            }
        }
#pragma unroll
        for (int it = 0; it < 2; ++it) {
            int lr = it * 8 + (lane >> 3);
            int c0 = (lane & 7) * 8;
            f32x4 v0 = *(const f32x4*)(&my[lr * 68 + c0]);
            f32x4 v1 = *(const f32x4*)(&my[lr * 68 + c0 + 4]);
            float* dst = ob + (size_t)(tqw + qr * 16 + lr) * SEQ + tkw + c0;
            *(f32x4*)dst       = v0;
            *(f32x4*)(dst + 4) = v1;
        }
    }
}

extern "C" void kernel_launch(void* const* d_in, const int* in_sizes, int n_in,
                              void* d_out, int out_size, void* d_ws, size_t ws_size,
                              hipStream_t stream) {
    const float* K   = (const float*)d_in[0];
    const float* Q   = (const float*)d_in[1];
    const float* Wk1 = (const float*)d_in[2];
    const float* bk1 = (const float*)d_in[3];
    const float* Wk2 = (const float*)d_in[4];
    const float* bk2 = (const float*)d_in[5];
    const float* Wk3 = (const float*)d_in[6];
    const float* bk3 = (const float*)d_in[7];
    const float* Wq1 = (const float*)d_in[8];
    const float* bq1 = (const float*)d_in[9];
    const float* Wq2 = (const float*)d_in[10];
    const float* bq2 = (const float*)d_in[11];
    const float* Wq3 = (const float*)d_in[12];
    const float* bq3 = (const float*)d_in[13];

    unsigned short* Kl   = (unsigned short*)d_ws;                 // [32][2048][32] bf16
    unsigned short* Ql   = Kl + (size_t)NH * SEQ * FD;            // +4 MB
    unsigned short* wimg = Ql + (size_t)NH * SEQ * FD;            // +4 MB (4.7 MB image)

    prep_weights<<<dim3(1152), dim3(256), 0, stream>>>(
        Wk1, Wk2, Wk3, Wq1, Wq2, Wq3, wimg);

    mlp_kernel<<<dim3(2 * NH * (SEQ / 64)), dim3(256), 0, stream>>>(
        K, Q, bk1, bk2, bk3, bq1, bq2, bq3, wimg, Kl, Ql);

    // TIMING PROBE (idempotent): identical second mlp dispatch.
    // dur(this round) - dur(round 5) = cost of one warm mlp_kernel pass.
    mlp_kernel<<<dim3(2 * NH * (SEQ / 64)), dim3(256), 0, stream>>>(
        K, Q, bk1, bk2, bk3, bq1, bq2, bq3, wimg, Kl, Ql);

    score_kernel<<<dim3(NH * 16 * 16), dim3(256), 0, stream>>>(
        Ql, Kl, (float*)d_out);
}

// Round 7
// 139.868 us; speedup vs baseline: 1.3402x; 1.3402x over previous
//
#include <hip/hip_runtime.h>

#define NH  32
#define SEQ 2048
#define DIM 128
#define FD  32

typedef short          short8 __attribute__((ext_vector_type(8)));
typedef float          f32x4  __attribute__((ext_vector_type(4)));
typedef unsigned short u16x8  __attribute__((ext_vector_type(8)));

static __device__ __forceinline__ unsigned short f2bf(float f) {
    unsigned int u = __builtin_bit_cast(unsigned int, f);
    u += 0x7fffu + ((u >> 16) & 1u);            // round-to-nearest-even
    return (unsigned short)(u >> 16);
}
static __device__ __forceinline__ float fexp(float x) {          // e^x
    return __builtin_amdgcn_exp2f(x * 1.44269504088896f);
}
static __device__ __forceinline__ float sigm(float x) {
    return __builtin_amdgcn_rcpf(1.0f + fexp(-x));
}
static __device__ __forceinline__ float silu_f(float x) { return x * sigm(x); }
static __device__ __forceinline__ float tanh_f(float x) {
    return 1.0f - 2.0f * __builtin_amdgcn_rcpf(fexp(2.0f * x) + 1.0f);
}

// ---------------------------------------------------------------------------
// Weight image in d_ws (ushort units), per src (0=K,1=Q), per head:
//   [W1: 128x128][W2: 128x128][W3: 32x128] bf16, rows XOR-swizzled:
//   element (r,c) stored at r*128 + (c ^ ((r&7)<<3))  (8-ushort block XOR).
#define WPH 36864
#define WPS (32 * WPH)

__global__ __launch_bounds__(256) void prep_weights(
    const float* __restrict__ Wk1, const float* __restrict__ Wk2,
    const float* __restrict__ Wk3, const float* __restrict__ Wq1,
    const float* __restrict__ Wq2, const float* __restrict__ Wq3,
    unsigned short* __restrict__ wimg) {
    int c = blockIdx.x * 256 + threadIdx.x;    // 294912 chunks of 8 elems
    int s = (c >= 147456) ? 1 : 0;
    c -= s * 147456;
    const float* src;
    int dst;
    int sB = s * WPS;
    if (c < 65536) {                            // W1
        int h = c >> 11, idx = c & 2047;
        int r = idx >> 4, jb = (idx & 15) * 8;
        src = (s ? Wq1 : Wk1) + h * 16384 + r * 128 + jb;
        dst = sB + h * WPH + r * 128 + (jb ^ ((r & 7) << 3));
    } else if (c < 131072) {                    // W2
        int cc = c - 65536;
        int h = cc >> 11, idx = cc & 2047;
        int r = idx >> 4, jb = (idx & 15) * 8;
        src = (s ? Wq2 : Wk2) + h * 16384 + r * 128 + jb;
        dst = sB + h * WPH + 16384 + r * 128 + (jb ^ ((r & 7) << 3));
    } else {                                    // W3
        int cc = c - 131072;
        int h = cc >> 9, idx = cc & 511;
        int r = idx >> 4, jb = (idx & 15) * 8;
        src = (s ? Wq3 : Wk3) + h * 4096 + r * 128 + jb;
        dst = sB + h * WPH + 32768 + r * 128 + (jb ^ ((r & 7) << 3));
    }
    f32x4 u0 = *(const f32x4*)src;
    f32x4 u1 = *(const f32x4*)(src + 4);
    u16x8 p;
    p[0] = f2bf(u0[0]); p[1] = f2bf(u0[1]); p[2] = f2bf(u0[2]); p[3] = f2bf(u0[3]);
    p[4] = f2bf(u1[0]); p[5] = f2bf(u1[1]); p[6] = f2bf(u1[2]); p[7] = f2bf(u1[3]);
    *(u16x8*)(&wimg[dst]) = p;
}

// ---------------------------------------------------------------------------
// MLP layers 1/2 (LDS weights), layer 3 from register-prefetched frags.
template <int OT, int ACT>
static __device__ __forceinline__ void compute_layer(
    const short8 a[4], const unsigned short* W,
    const float* __restrict__ bias, unsigned short* dst, int lane, int wid) {
    int r0 = lane & 15, q = lane >> 4, kb = q * 8;
#pragma unroll
    for (int ot = 0; ot < OT; ++ot) {
        int wrow = ot * 16 + r0;
        int sw   = (wrow & 7) << 3;
        short8 b[4];
#pragma unroll
        for (int ks = 0; ks < 4; ++ks)
            b[ks] = *(const short8*)(&W[wrow * 128 + ((ks * 32 + kb) ^ sw)]);
        f32x4 acc = {0.f, 0.f, 0.f, 0.f};
#pragma unroll
        for (int ks = 0; ks < 4; ++ks)
            acc = __builtin_amdgcn_mfma_f32_16x16x32_bf16(a[ks], b[ks], acc, 0, 0, 0);
        float bv = bias[wrow];
#pragma unroll
        for (int r = 0; r < 4; ++r) {
            float y = acc[r] + bv;
            float v = (ACT == 0) ? silu_f(y) : tanh_f(y);
            int orow = wid * 16 + q * 4 + r;
            int ocol = ot * 16 + r0;
            dst[orow * 128 + (ocol ^ ((orow & 7) << 3))] = f2bf(v);
        }
    }
}

static __device__ __forceinline__ void compute_layer3_reg(
    const short8 a[4], const short8 w3f[2][4],
    const float* __restrict__ bias, unsigned short* dst, int lane, int wid) {
    int r0 = lane & 15, q = lane >> 4;
#pragma unroll
    for (int ot = 0; ot < 2; ++ot) {
        f32x4 acc = {0.f, 0.f, 0.f, 0.f};
#pragma unroll
        for (int ks = 0; ks < 4; ++ks)
            acc = __builtin_amdgcn_mfma_f32_16x16x32_bf16(a[ks], w3f[ot][ks], acc, 0, 0, 0);
        float bv = bias[ot * 16 + r0];
#pragma unroll
        for (int r = 0; r < 4; ++r) {
            float v = tanh_f(acc[r] + bv);
            dst[(wid * 16 + q * 4 + r) * FD + ot * 16 + r0] = f2bf(v);
        }
    }
}

__global__ __launch_bounds__(256) void mlp_kernel(
    const float* __restrict__ K,  const float* __restrict__ Q,
    const float* __restrict__ bk1, const float* __restrict__ bk2,
    const float* __restrict__ bk3, const float* __restrict__ bq1,
    const float* __restrict__ bq2, const float* __restrict__ bq3,
    const unsigned short* __restrict__ wimg,
    unsigned short* __restrict__ Kl, unsigned short* __restrict__ Ql) {
    __shared__ unsigned short wb[128 * 128];   // 32 KB  W1 then W2
    __shared__ unsigned short act[64 * 128];   // 16 KB
    __shared__ unsigned short outb[64 * FD];   // 4 KB   -> 52 KB total (3 blk/CU)
    int raw = blockIdx.x;
    int bid = (raw & 7) * 256 + (raw >> 3);    // XCD swizzle (2048 % 8 == 0)
    int tb  = bid & 31;
    int h   = (bid >> 5) & 31;
    int s   = bid >> 10;

    const float* X  = s ? Q : K;
    const unsigned short* Wb = wimg + s * WPS + h * WPH;
    const float* B1 = (s ? bq1 : bk1) + h * 128;
    const float* B2 = (s ? bq2 : bk2) + h * 128;
    const float* B3 = (s ? bq3 : bk3) + h * FD;
    unsigned short* gout = (s ? Ql : Kl) + ((size_t)h * SEQ + (size_t)tb * 64) * FD;

    int tid = threadIdx.x, lane = tid & 63, wid = tid >> 6;
    int r0 = lane & 15, kb = (lane >> 4) * 8;

    // W3 fragments: issue-early (L2/L3), consumed only in layer 3
    short8 w3f[2][4];
    {
        const unsigned short* W3g = Wb + 32768;
        int sw = (r0 & 7) << 3;
#pragma unroll
        for (int ot = 0; ot < 2; ++ot)
#pragma unroll
            for (int ks = 0; ks < 4; ++ks)
                w3f[ot][ks] = *(const short8*)(&W3g[(ot * 16 + r0) * 128 + ((ks * 32 + kb) ^ sw)]);
    }

    const u16x8* wsrc = (const u16x8*)Wb;
#pragma unroll
    for (int i = 0; i < 8; ++i)
        *(u16x8*)(&wb[(i * 256 + tid) * 8]) = wsrc[i * 256 + tid];

    short8 a[4];
    const float* xs = X + ((size_t)h * SEQ + (size_t)tb * 64) * DIM;
    int row = wid * 16 + r0;
#pragma unroll
    for (int ks = 0; ks < 4; ++ks) {
        const float* p = xs + row * 128 + ks * 32 + kb;
        f32x4 u0 = *(const f32x4*)p;
        f32x4 u1 = *(const f32x4*)(p + 4);
        short8 t;
        t[0] = f2bf(u0[0]); t[1] = f2bf(u0[1]); t[2] = f2bf(u0[2]); t[3] = f2bf(u0[3]);
        t[4] = f2bf(u1[0]); t[5] = f2bf(u1[1]); t[6] = f2bf(u1[2]); t[7] = f2bf(u1[3]);
        a[ks] = t;
    }
    __syncthreads();
    compute_layer<8, 0>(a, wb, B1, act, lane, wid);          // h1 -> act
    __syncthreads();
#pragma unroll
    for (int i = 0; i < 8; ++i)
        *(u16x8*)(&wb[(i * 256 + tid) * 8]) = wsrc[2048 + i * 256 + tid];
    __syncthreads();
    {
        int sw = (row & 7) << 3;
#pragma unroll
        for (int ks = 0; ks < 4; ++ks)
            a[ks] = *(const short8*)(&act[row * 128 + ((ks * 32 + kb) ^ sw)]);
    }
    compute_layer<8, 0>(a, wb, B2, act, lane, wid);          // h2 -> act
    {
        int sw = (row & 7) << 3;
#pragma unroll
        for (int ks = 0; ks < 4; ++ks)
            a[ks] = *(const short8*)(&act[row * 128 + ((ks * 32 + kb) ^ sw)]);
    }
    compute_layer3_reg(a, w3f, B3, outb, lane, wid);         // out -> outb
    __syncthreads();
    *(u16x8*)(gout + tid * 8) = *(const u16x8*)(&outb[tid * 8]);
}

// ---------------------------------------------------------------------------
// scores: 128x128 per block; wave owns 128 rows x 32 cols. Per 16-row phase:
// compute+sigmoid -> block-wide 16x130 bounce strip (double-buffered) ->
// cooperative store where EVERY instruction covers 2 full rows x 512 B
// (no intra-line holes). One barrier per phase; stores overlap next MFMA.
__global__ __launch_bounds__(256) void score_kernel(
    const unsigned short* __restrict__ Ql, const unsigned short* __restrict__ Kl,
    float* __restrict__ out) {
    int bid = blockIdx.x;
    int h   = bid >> 8;
    int tr  = (bid >> 4) & 15;
    int tc  = bid & 15;
    int tq0 = tr * 128, tk0 = tc * 128;
    int tid = threadIdx.x;
    float* ob = out + (size_t)h * SEQ * SEQ;

    if (tc > tr) {                              // fully masked: sigmoid(-inf) = 0
        f32x4 z = {0.f, 0.f, 0.f, 0.f};
        for (int it = 0; it < 16; ++it) {
            int row = tq0 + it * 8 + (tid >> 5);
            int c0  = tk0 + (tid & 31) * 4;
            *(f32x4*)(ob + (size_t)row * SEQ + c0) = z;
        }
        return;
    }
    bool diag = (tc == tr);
    __shared__ float sb[2][16 * 130];           // 16.6 KB double-buffered strip
    int lane = tid & 63;
    int wid  = tid >> 6;                        // wave owns cols wid*32..+31
    int r0   = lane & 15;
    int kb   = (lane >> 4) * 8;

    short8 aq[8], bk[2];
#pragma unroll
    for (int i = 0; i < 8; ++i)
        aq[i] = *(const short8*)(Ql + ((size_t)h * SEQ + tq0 + i * 16 + r0) * FD + kb);
#pragma unroll
    for (int ct = 0; ct < 2; ++ct)
        bk[ct] = *(const short8*)(Kl + ((size_t)h * SEQ + tk0 + wid * 32 + ct * 16 + r0) * FD + kb);

#pragma unroll
    for (int p = 0; p < 8; ++p) {
        float* my = sb[p & 1];
#pragma unroll
        for (int ct = 0; ct < 2; ++ct) {
            f32x4 acc = {0.f, 0.f, 0.f, 0.f};
            acc = __builtin_amdgcn_mfma_f32_16x16x32_bf16(aq[p], bk[ct], acc, 0, 0, 0);
#pragma unroll
            for (int r = 0; r < 4; ++r) {
                int lr  = (lane >> 4) * 4 + r;
                int col = wid * 32 + ct * 16 + r0;
                float o = sigm(acc[r] - 0.5f);
                if (diag && (tk0 + col) > (tq0 + p * 16 + lr)) o = 0.0f;
                my[lr * 130 + col] = o;
            }
        }
        __syncthreads();
        // 16 rows x 128 f32: instr = 2 full rows x 512 B, fully covered
#pragma unroll
        for (int j = 0; j < 2; ++j) {
            int row = (tid >> 5) + j * 8;
            int c0  = (tid & 31) * 4;
            f32x4 v = *(const f32x4*)(&my[row * 130 + c0]);
            *(f32x4*)(ob + (size_t)(tq0 + p * 16 + row) * SEQ + tk0 + c0) = v;
        }
    }
}

extern "C" void kernel_launch(void* const* d_in, const int* in_sizes, int n_in,
                              void* d_out, int out_size, void* d_ws, size_t ws_size,
                              hipStream_t stream) {
    const float* K   = (const float*)d_in[0];
    const float* Q   = (const float*)d_in[1];
    const float* Wk1 = (const float*)d_in[2];
    const float* bk1 = (const float*)d_in[3];
    const float* Wk2 = (const float*)d_in[4];
    const float* bk2 = (const float*)d_in[5];
    const float* Wk3 = (const float*)d_in[6];
    const float* bk3 = (const float*)d_in[7];
    const float* Wq1 = (const float*)d_in[8];
    const float* bq1 = (const float*)d_in[9];
    const float* Wq2 = (const float*)d_in[10];
    const float* bq2 = (const float*)d_in[11];
    const float* Wq3 = (const float*)d_in[12];
    const float* bq3 = (const float*)d_in[13];

    unsigned short* Kl   = (unsigned short*)d_ws;                 // [32][2048][32] bf16
    unsigned short* Ql   = Kl + (size_t)NH * SEQ * FD;            // +4 MB
    unsigned short* wimg = Ql + (size_t)NH * SEQ * FD;            // +4 MB (4.7 MB image)

    prep_weights<<<dim3(1152), dim3(256), 0, stream>>>(
        Wk1, Wk2, Wk3, Wq1, Wq2, Wq3, wimg);

    mlp_kernel<<<dim3(2 * NH * (SEQ / 64)), dim3(256), 0, stream>>>(
        K, Q, bk1, bk2, bk3, bq1, bq2, bq3, wimg, Kl, Ql);

    score_kernel<<<dim3(NH * 16 * 16), dim3(256), 0, stream>>>(
        Ql, Kl, (float*)d_out);
}